// Round 3
// baseline (288.941 us; speedup 1.0000x reference)
//
#include <hip/hip_runtime.h>

// Problem constants (fixed by setup_inputs)
#define N_IMG 4
#define E_DIM 16
#define H_DIM 768
#define W_DIM 768
#define P_PIX (H_DIM * W_DIM)   // 589824 pixels per image
#define C_CL 32

#define DELTA_VAR 0.5f
#define DELTA_DIST 2.0f
#define GAMMA_W 0.001f
#define EPS_F 1e-12f

// Workspace layout (floats):
//   [0,    2048): sums   [N][C][E]
//   [2048, 2176): counts [N][C]
//   [2176, 2180): varsum [N]  (Sigma_p h^2/cnt per image)
#define WS_SUMS 0
#define WS_CNT 2048
#define WS_VAR 2176
#define WS_TOTAL 2180

#define PX_PER_BLOCK 2048
#define BLOCKS_X (P_PIX / PX_PER_BLOCK)  // 288

typedef __attribute__((ext_vector_type(8))) short short8;
typedef __attribute__((ext_vector_type(16))) float float16v;

__device__ __forceinline__ void gatomic_add(float* p, float v) {
#if defined(__HIP_DEVICE_COMPILE__)
  unsafeAtomicAdd(p, v);  // hw global_atomic_add_f32 on gfx950
#else
  atomicAdd(p, v);
#endif
}

// bf16 truncation (round-toward-zero): unbiased for sums of symmetric data,
// 1 VALU op per element instead of 4 for RNE.
__device__ __forceinline__ short f2bf(float f) {
  return (short)(__float_as_uint(f) >> 16);
}

// ---------------------------------------------------------------------------
// Pass 1: sums[c][e] and counts[c] via one MFMA chain.
//   D[m][n] = Sigma_k A[m][k] * B[k][n]
//   A[m][k] = onehot(lab[base+k] == m)           (exact in bf16: 1.0/0.0)
//   B[k][n] = x[base+k][e=n] for n<16; 1.0 for n==16 (counts); 0 otherwise.
// Fragment maps (A: m=lane&31, k=(lane>>5)*8+j ; B: n=lane&31, same k) are
// symmetric duals, so any consistent k-permutation cancels in the sum.
// ---------------------------------------------------------------------------
__global__ __launch_bounds__(256) void pass1(const float* __restrict__ input,
                                             const int* __restrict__ target,
                                             float* __restrict__ ws) {
  __shared__ float s_red[4 * 16 * 64];  // [wave][reg][lane], 16 KB
  const int tid = threadIdx.x;
  const int wv = tid >> 6, l = tid & 63;
  const int n = blockIdx.y;
  const int m = l & 31;    // A-row (cluster) / B-col (e or ones)
  const int half = l >> 5; // k-half
  const bool is_e = (m < E_DIM);
  const bool is_one = (m == E_DIM);

  const int base0 = blockIdx.x * PX_PER_BLOCK + wv * 512 + half * 8;
  const int* tgt = target + (size_t)n * P_PIX + base0;
  const float* bptr =
      input + ((size_t)n * E_DIM + (is_e ? m : 0)) * P_PIX + base0;

  const short ONE = 0x3F80;  // bf16(1.0)
  float16v acc;
#pragma unroll
  for (int i = 0; i < 16; ++i) acc[i] = 0.f;

  for (int s = 0; s < 32; ++s) {  // 512 px per wave, 16 px per MFMA
    const int off = s * 16;
    const int4 lab0 = *reinterpret_cast<const int4*>(tgt + off);
    const int4 lab1 = *reinterpret_cast<const int4*>(tgt + off + 4);
    short8 a;
    a[0] = (lab0.x == m) ? ONE : 0;
    a[1] = (lab0.y == m) ? ONE : 0;
    a[2] = (lab0.z == m) ? ONE : 0;
    a[3] = (lab0.w == m) ? ONE : 0;
    a[4] = (lab1.x == m) ? ONE : 0;
    a[5] = (lab1.y == m) ? ONE : 0;
    a[6] = (lab1.z == m) ? ONE : 0;
    a[7] = (lab1.w == m) ? ONE : 0;
    short8 b;
    if (is_e) {
      const float4 v0 = *reinterpret_cast<const float4*>(bptr + off);
      const float4 v1 = *reinterpret_cast<const float4*>(bptr + off + 4);
      b[0] = f2bf(v0.x); b[1] = f2bf(v0.y); b[2] = f2bf(v0.z); b[3] = f2bf(v0.w);
      b[4] = f2bf(v1.x); b[5] = f2bf(v1.y); b[6] = f2bf(v1.z); b[7] = f2bf(v1.w);
    } else {
      const short fill = is_one ? ONE : (short)0;
#pragma unroll
      for (int j = 0; j < 8; ++j) b[j] = fill;
    }
    acc = __builtin_amdgcn_mfma_f32_32x32x16_bf16(a, b, acc, 0, 0, 0);
  }

  // Cross-wave reduce in LDS, then one global atomic per (row,col).
#pragma unroll
  for (int r = 0; r < 16; ++r) s_red[wv * 1024 + r * 64 + l] = acc[r];
  __syncthreads();

  // C/D layout: col = lane&31, row = (reg&3) + 8*(reg>>2) + 4*(lane>>5)
  for (int i = tid; i < C_CL * 17; i += 256) {
    const int row = i / 17;        // cluster
    const int col = i - row * 17;  // e (0..15) or count (16)
    const int lane = col | (((row >> 2) & 1) << 5);
    const int reg = (row & 3) | ((row >> 3) << 2);
    const int idx = reg * 64 + lane;
    const float v = s_red[idx] + s_red[1024 + idx] + s_red[2048 + idx] +
                    s_red[3072 + idx];
    if (col < 16)
      gatomic_add(&ws[WS_SUMS + n * C_CL * E_DIM + row * E_DIM + col], v);
    else
      gatomic_add(&ws[WS_CNT + n * C_CL + row], v);
  }
}

// ---------------------------------------------------------------------------
// Pass 2: variance term without histograms:
//   Sigma_c (Sigma_{p in c} h^2)/cnt_c = Sigma_p h^2_p * invcnt[lab_p]
// One scalar accumulator per thread, one atomic per block.
// ---------------------------------------------------------------------------
__global__ __launch_bounds__(256) void pass2(const float* __restrict__ input,
                                             const int* __restrict__ target,
                                             float* __restrict__ ws) {
  __shared__ float s_mean[C_CL * 17];  // stride 17: bank=(17c+e)%32, bijective
  __shared__ float s_invc[C_CL];
  __shared__ float s_red[256];
  const int tid = threadIdx.x;
  const int n = blockIdx.y;
  for (int i = tid; i < C_CL * E_DIM; i += 256) {
    const int c = i >> 4, e = i & 15;
    s_mean[c * 17 + e] =
        ws[WS_SUMS + n * C_CL * E_DIM + i] / ws[WS_CNT + n * C_CL + c];
  }
  if (tid < C_CL) s_invc[tid] = 1.0f / ws[WS_CNT + n * C_CL + tid];
  __syncthreads();

  const int base = blockIdx.x * PX_PER_BLOCK;
  const float* inp = input + (size_t)n * E_DIM * P_PIX;
  const int* tgt = target + (size_t)n * P_PIX;

  float acc = 0.f;
#pragma unroll
  for (int s = 0; s < 2; ++s) {
    const int p = base + s * 1024 + tid * 4;
    const int4 lab = *reinterpret_cast<const int4*>(tgt + p);
    float ax = 0.f, ay = 0.f, az = 0.f, aw = 0.f;
#pragma unroll
    for (int e = 0; e < E_DIM; ++e) {
      const float4 v =
          *reinterpret_cast<const float4*>(inp + (size_t)e * P_PIX + p);
      const float dx = v.x - s_mean[lab.x * 17 + e];
      const float dy = v.y - s_mean[lab.y * 17 + e];
      const float dz = v.z - s_mean[lab.z * 17 + e];
      const float dw = v.w - s_mean[lab.w * 17 + e];
      ax += dx * dx; ay += dy * dy; az += dz * dz; aw += dw * dw;
    }
    float d, h;
    d = sqrtf(fmaxf(ax, EPS_F)); h = fmaxf(d - DELTA_VAR, 0.f);
    acc += h * h * s_invc[lab.x];
    d = sqrtf(fmaxf(ay, EPS_F)); h = fmaxf(d - DELTA_VAR, 0.f);
    acc += h * h * s_invc[lab.y];
    d = sqrtf(fmaxf(az, EPS_F)); h = fmaxf(d - DELTA_VAR, 0.f);
    acc += h * h * s_invc[lab.z];
    d = sqrtf(fmaxf(aw, EPS_F)); h = fmaxf(d - DELTA_VAR, 0.f);
    acc += h * h * s_invc[lab.w];
  }

  s_red[tid] = acc;
  __syncthreads();
  for (int s2 = 128; s2 > 0; s2 >>= 1) {
    if (tid < s2) s_red[tid] += s_red[tid + s2];
    __syncthreads();
  }
  if (tid == 0) gatomic_add(&ws[WS_VAR + n], s_red[0]);
}

// ---------------------------------------------------------------------------
// Finalize: variance + pairwise distance + regularizer -> scalar.
// ---------------------------------------------------------------------------
__global__ __launch_bounds__(256) void finalize(const float* __restrict__ ws,
                                                float* __restrict__ out) {
  __shared__ float s_mean[N_IMG * C_CL * E_DIM];  // 2048 floats
  __shared__ float red[256];
  const int tid = threadIdx.x;
  for (int i = tid; i < N_IMG * C_CL * E_DIM; i += 256) {
    s_mean[i] = ws[WS_SUMS + i] / ws[WS_CNT + (i >> 4)];
  }
  __syncthreads();

  float acc = 0.f;
  // variance terms (per-image scalars)
  for (int i = tid; i < N_IMG; i += 256) acc += ws[WS_VAR + i] * (1.0f / C_CL);
  // regularizer over 128 (n,c) cells
  for (int i = tid; i < N_IMG * C_CL; i += 256) {
    float nrm2 = 0.f;
    const float* m = s_mean + i * E_DIM;
#pragma unroll
    for (int e = 0; e < E_DIM; ++e) nrm2 += m[e] * m[e];
    acc += GAMMA_W * sqrtf(fmaxf(nrm2, EPS_F)) * (1.0f / C_CL);
  }
  // pairwise distance term: 4 * 32 * 32 cells
  for (int t = tid; t < N_IMG * C_CL * C_CL; t += 256) {
    const int n = t / (C_CL * C_CL);
    const int r = t - n * C_CL * C_CL;
    const int a = r >> 5, b = r & 31;
    if (a != b) {
      const float* ma = s_mean + (n * C_CL + a) * E_DIM;
      const float* mb = s_mean + (n * C_CL + b) * E_DIM;
      float d2 = 0.f;
#pragma unroll
      for (int e = 0; e < E_DIM; ++e) {
        const float df = ma[e] - mb[e];
        d2 += df * df;
      }
      const float dist = sqrtf(fmaxf(d2, EPS_F));
      const float hd = fmaxf(2.f * DELTA_DIST - dist, 0.f);
      acc += hd * hd * (1.0f / (C_CL * (C_CL - 1)));
    }
  }

  red[tid] = acc;
  __syncthreads();
  for (int s = 128; s > 0; s >>= 1) {
    if (tid < s) red[tid] += red[tid + s];
    __syncthreads();
  }
  if (tid == 0) out[0] = red[0] * (1.0f / N_IMG);
}

extern "C" void kernel_launch(void* const* d_in, const int* in_sizes, int n_in,
                              void* d_out, int out_size, void* d_ws,
                              size_t ws_size, hipStream_t stream) {
  const float* input = (const float*)d_in[0];
  const int* target = (const int*)d_in[1];
  float* ws = (float*)d_ws;
  float* out = (float*)d_out;

  hipMemsetAsync(ws, 0, WS_TOTAL * sizeof(float), stream);
  dim3 grid(BLOCKS_X, N_IMG);
  pass1<<<grid, 256, 0, stream>>>(input, target, ws);
  pass2<<<grid, 256, 0, stream>>>(input, target, ws);
  finalize<<<1, 256, 0, stream>>>(ws, out);
}